// Round 3
// baseline (2322.209 us; speedup 1.0000x reference)
//
#include <hip/hip_runtime.h>

// ---------------------------------------------------------------------------
// MultiDimensionalLSTM on MI355X.
// B=32, C=32, Y=X=128, win 4x4 -> grid 32x32 cells, F=512, R=128, gates 5R=640.
// Input projection hoisted to one split-bf16 MFMA GEMM. Recurrence runs in ONE
// persistent kernel: 512 WGs (16 r-slices x 32 rows) sweep w=0..31 with
// device-scope flag sync along the 2D wavefront. Split-bf16 (hi+lo, 3-term
// MFMA) everywhere; c-state fp32 (slice-local); h carried as bf16 hi+lo pair.
// ---------------------------------------------------------------------------

typedef unsigned short u16;
typedef __attribute__((ext_vector_type(8))) short short8;     // 8 bf16 (4 VGPRs)
typedef __attribute__((ext_vector_type(8))) unsigned short us8;
typedef __attribute__((ext_vector_type(4))) float floatx4;

__device__ inline u16 f2bf(float f) {               // RNE fp32 -> bf16
  unsigned u = __float_as_uint(f);
  u += 0x7fffu + ((u >> 16) & 1u);
  return (u16)(u >> 16);
}
__device__ inline float bf2f(u16 v) { return __uint_as_float(((unsigned)v) << 16); }

__device__ inline void async16(u16* lds, const u16* g) {
  // dest = wave-uniform base + lane*16 (caller must arrange this)
  __builtin_amdgcn_global_load_lds((const __attribute__((address_space(1))) void*)g,
                                   (__attribute__((address_space(3))) void*)lds, 16, 0, 0);
}

__device__ inline float sigf(float x) { return 1.f / (1.f + __expf(-x)); }
__device__ inline float tanh_fast(float x) { return 1.f - 2.f / (__expf(2.f * x) + 1.f); }

__device__ inline void waitflag(int* f, int target) {
  while (__hip_atomic_load(f, __ATOMIC_RELAXED, __HIP_MEMORY_SCOPE_AGENT) < target) {}
  (void)__hip_atomic_load(f, __ATOMIC_ACQUIRE, __HIP_MEMORY_SCOPE_AGENT);
}

// ---------------------------------------------------------------------------
// Prep 1: W [768][640] fp32 -> WxT_{h,l} [640 pcol][512 k], WhT_{h,l} [640][256],
// biasp [640]. pcol = r*5+g  <->  orig col g*128+r (gate-interleaved).
// WhT row k: k<128 -> W row 512+k (up h1), k>=128 -> W row 640+(k-128) (left h2).
// ---------------------------------------------------------------------------
__global__ __launch_bounds__(256) void k_wprep(const float* __restrict__ W,
                                               const float* __restrict__ bias,
                                               u16* __restrict__ WxT_h, u16* __restrict__ WxT_l,
                                               u16* __restrict__ WhT_h, u16* __restrict__ WhT_l,
                                               float* __restrict__ biasp) {
  int pcol = blockIdx.x;                       // 0..639
  int col  = (pcol % 5) * 128 + pcol / 5;      // original gate column
  for (int k = threadIdx.x; k < 768; k += 256) {
    float v = W[(size_t)k * 640 + col];
    u16 hi = f2bf(v);
    u16 lo = f2bf(v - bf2f(hi));
    if (k < 512) { WxT_h[(size_t)pcol * 512 + k] = hi; WxT_l[(size_t)pcol * 512 + k] = lo; }
    else { WhT_h[(size_t)pcol * 256 + (k - 512)] = hi; WhT_l[(size_t)pcol * 256 + (k - 512)] = lo; }
  }
  if (threadIdx.x == 0) biasp[pcol] = bias[col];
}

// ---------------------------------------------------------------------------
// Prep 2: gather x [B,C,Y,X] -> xs hi/lo [t=0..1023][b=0..31][f=0..511].
// xs[t][b][f] = x[b][f&31][t>>3][(t&7)*16 + (f>>5)]
// ---------------------------------------------------------------------------
__global__ __launch_bounds__(256) void k_xgather(const float* __restrict__ x,
                                                 u16* __restrict__ xs_h,
                                                 u16* __restrict__ xs_l) {
  int lane = threadIdx.x & 63;
  int pair = blockIdx.x * 4 + (threadIdx.x >> 6);  // 0..32767 == t*32+b
  int t = pair >> 5, b = pair & 31;
  int y = t >> 3, x0 = (t & 7) * 16;
  int j = lane >> 2;                // f>>5, 0..15
  int cbase = (lane & 3) * 8;       // f&31 base
  const float* src = x + ((size_t)b * 32 * 128 + y) * 128 + x0 + j;
  us8 vh, vl;
#pragma unroll
  for (int u = 0; u < 8; ++u) {
    float f = src[(size_t)(cbase + u) * 16384];
    u16 hi = f2bf(f);
    vh[u] = hi;
    vl[u] = f2bf(f - bf2f(hi));
  }
  *(us8*)(xs_h + (size_t)pair * 512 + lane * 8) = vh;
  *(us8*)(xs_l + (size_t)pair * 512 + lane * 8) = vl;
}

// ---------------------------------------------------------------------------
// Input GEMM (split-bf16): G[m][pcol] = biasp + sum_k xs[m][k]*WxT[pcol][k]
// M=32768, N=640, K=512. 128x128 tile, BK=32, 4 waves, 4x4 16x16x32 acc/wave.
// ---------------------------------------------------------------------------
__global__ __launch_bounds__(256) void k_gemm_in(const u16* __restrict__ xs_h,
                                                 const u16* __restrict__ xs_l,
                                                 const u16* __restrict__ WxT_h,
                                                 const u16* __restrict__ WxT_l,
                                                 const float* __restrict__ biasp,
                                                 float* __restrict__ Gp) {
  __shared__ u16 Ah[128 * 32], Al[128 * 32];   // [m][k], 8 KB each
  __shared__ u16 Bh[128 * 32], Bl[128 * 32];   // [n][k]
  const int tid = threadIdx.x;
  const int wv = tid >> 6, lane = tid & 63;
  const int quad = lane >> 4, l16 = lane & 15;
  const int m0 = blockIdx.x * 128;
  const int n0 = blockIdx.y * 128;
  const int arow = lane >> 2;            // row within 16-row chunk
  const int acol = (lane & 3) * 8;       // u16 offset within 64B row

  floatx4 acc[4][4] = {};

  for (int kt = 0; kt < 512; kt += 32) {
#pragma unroll
    for (int i = 0; i < 2; ++i) {
      int chunk = wv * 2 + i;            // 0..7, 16 rows each
      int row = chunk * 16 + arow;
      size_t aoff = (size_t)(m0 + row) * 512 + kt + acol;
      size_t boff = (size_t)(n0 + row) * 512 + kt + acol;
      async16(&Ah[chunk * 512 + lane * 8], xs_h + aoff);
      async16(&Al[chunk * 512 + lane * 8], xs_l + aoff);
      async16(&Bh[chunk * 512 + lane * 8], WxT_h + boff);
      async16(&Bl[chunk * 512 + lane * 8], WxT_l + boff);
    }
    __syncthreads();
    short8 afh[4], afl[4], bfh[4], bfl[4];
#pragma unroll
    for (int mt = 0; mt < 4; ++mt) {
      int ro = ((wv & 1) * 64 + mt * 16 + l16) * 32 + quad * 8;
      afh[mt] = *(const short8*)&Ah[ro];
      afl[mt] = *(const short8*)&Al[ro];
    }
#pragma unroll
    for (int nt = 0; nt < 4; ++nt) {
      int ro = ((wv >> 1) * 64 + nt * 16 + l16) * 32 + quad * 8;
      bfh[nt] = *(const short8*)&Bh[ro];
      bfl[nt] = *(const short8*)&Bl[ro];
    }
#pragma unroll
    for (int mt = 0; mt < 4; ++mt)
#pragma unroll
      for (int nt = 0; nt < 4; ++nt) {
        floatx4 a = acc[mt][nt];
        a = __builtin_amdgcn_mfma_f32_16x16x32_bf16(afl[mt], bfh[nt], a, 0, 0, 0);
        a = __builtin_amdgcn_mfma_f32_16x16x32_bf16(afh[mt], bfl[nt], a, 0, 0, 0);
        a = __builtin_amdgcn_mfma_f32_16x16x32_bf16(afh[mt], bfh[nt], a, 0, 0, 0);
        acc[mt][nt] = a;
      }
    __syncthreads();
  }
#pragma unroll
  for (int nt = 0; nt < 4; ++nt) {
    int n = n0 + (wv >> 1) * 64 + nt * 16 + l16;
    float bv = biasp[n];
#pragma unroll
    for (int mt = 0; mt < 4; ++mt) {
      int m = m0 + (wv & 1) * 64 + mt * 16 + quad * 4;
#pragma unroll
      for (int r = 0; r < 4; ++r)
        Gp[(size_t)(m + r) * 640 + n] = acc[mt][nt][r] + bv;
    }
  }
}

// ---------------------------------------------------------------------------
// Persistent recurrence. Grid 512 = (si 0..15) * 32 + h; block 128 (2 waves).
// blockIdx = h + 32*si so all slices of row h land on XCD h%8 (locality hint).
// Slice si owns pcols [si*40, si*40+40) == r in [si*8, si*8+8).
// WhT slice (hi+lo) resident in LDS for the whole sweep; n padded 40->48 for
// clean 16-wide MFMA tiles (cols 40..47 garbage, masked in epilogue).
// Sync: flags[t] counts finished slices (target 16); relaxed spin + acquire;
// producers __threadfence() + release-increment. c-state is slice-local in r,
// so only the h vector (MFMA A operand) needs cross-WG visibility.
// Co-residency: LDS 53 KB -> 3 WGs/CU capacity, 512 <= 768. Deadlock-free.
// ---------------------------------------------------------------------------
__global__ __launch_bounds__(128) void k_rec(const u16* __restrict__ WhT_h,
                                             const u16* __restrict__ WhT_l,
                                             const float* __restrict__ Gp,
                                             float* __restrict__ cbuf,
                                             u16* __restrict__ hbf_h,
                                             u16* __restrict__ hbf_l,
                                             float* __restrict__ out,
                                             int* __restrict__ flags) {
  __shared__ u16 Bh[48 * 256], Bl[48 * 256];   // 24 KB each
  __shared__ float Gs[32 * 40];                // 5 KB
  const int h = blockIdx.x & 31, si = blockIdx.x >> 5;  // si 0..15
  const int tid = threadIdx.x;
  const int wv = tid >> 6, lane = tid & 63;
  const int quad = lane >> 4, l16 = lane & 15;

  { // stage B slice rows [si*40, si*40+40), 512 B/row, 2 rows per wave-call
    const u16* sh = WhT_h + (size_t)si * 40 * 256;
    const u16* sl = WhT_l + (size_t)si * 40 * 256;
#pragma unroll
    for (int c = 0; c < 10; ++c) {
      int rb = c * 4 + wv * 2;
      async16(&Bh[rb * 256 + lane * 8], sh + (size_t)rb * 256 + lane * 8);
      async16(&Bl[rb * 256 + lane * 8], sl + (size_t)rb * 256 + lane * 8);
    }
  }
  __syncthreads();

  const short8 z8 = {0, 0, 0, 0, 0, 0, 0, 0};
  for (int w = 0; w < 32; ++w) {
    const int t = h * 32 + w;
    const bool upok = t > 32;            // faithful off-by-one: (1,0) gets no up
    const bool leftok = w > 0;
    if (upok)   waitflag(&flags[t - 32], 16);
    if (leftok) waitflag(&flags[t - 1], 16);

    floatx4 acc[3] = {};
#pragma unroll
    for (int ks = 0; ks < 8; ++ks) {
      // A: Hcat[b][k]; k<128 -> h_up (t-32), k>=128 -> h_left (t-1)
      const bool ok = (ks < 4) ? upok : leftok;
      const int tt = (ks < 4) ? (t - 32) : (t - 1);
      short8 ah = z8, al = z8;
      if (ok) {
        size_t ao = ((size_t)tt * 32 + wv * 16 + l16) * 128 + (ks & 3) * 32 + quad * 8;
        ah = *(const short8*)(hbf_h + ao);
        al = *(const short8*)(hbf_l + ao);
      }
#pragma unroll
      for (int nt = 0; nt < 3; ++nt) {
        int bo = (nt * 16 + l16) * 256 + ks * 32 + quad * 8;
        short8 bh = *(const short8*)&Bh[bo];
        short8 bl = *(const short8*)&Bl[bo];
        floatx4 a = acc[nt];
        a = __builtin_amdgcn_mfma_f32_16x16x32_bf16(al, bh, a, 0, 0, 0);
        a = __builtin_amdgcn_mfma_f32_16x16x32_bf16(ah, bl, a, 0, 0, 0);
        a = __builtin_amdgcn_mfma_f32_16x16x32_bf16(ah, bh, a, 0, 0, 0);
        acc[nt] = a;
      }
    }

    // gates = acc + Gp -> Gs  (D: row=quad*4+r -> b, col=l16 -> n-local)
#pragma unroll
    for (int nt = 0; nt < 3; ++nt) {
      int pl = nt * 16 + l16;
      if (pl < 40) {
#pragma unroll
        for (int r = 0; r < 4; ++r) {
          int b = wv * 16 + quad * 4 + r;
          Gs[b * 40 + pl] = acc[nt][r] + Gp[((size_t)t * 32 + b) * 640 + si * 40 + pl];
        }
      }
    }
    __syncthreads();

    // nonlinearity + state update: 32 b x 8 r = 256 pairs, 2 per thread
#pragma unroll
    for (int u = 0; u < 2; ++u) {
      int pair = u * 128 + tid;
      int b = pair >> 3, rr = pair & 7;
      int r = si * 8 + rr;
      const float* gp = &Gs[b * 40 + rr * 5];
      float gi = gp[0], gj = gp[1], g1 = gp[2], g2 = gp[3], go = gp[4];
      float c1 = upok   ? cbuf[((size_t)(t - 32) * 32 + b) * 128 + r] : 0.f;
      float c2 = leftok ? cbuf[((size_t)(t - 1) * 32 + b) * 128 + r] : 0.f;
      float nc_ = c1 * sigf(g1) + c2 * sigf(g2) + sigf(gi) * tanh_fast(gj);
      float nh  = tanh_fast(nc_) * sigf(go);
      cbuf[((size_t)t * 32 + b) * 128 + r] = nc_;
      u16 hh = f2bf(nh);
      hbf_h[((size_t)t * 32 + b) * 128 + r] = hh;
      hbf_l[((size_t)t * 32 + b) * 128 + r] = f2bf(nh - bf2f(hh));
      out[(((size_t)b * 32 + h) * 32 + w) * 128 + r] = nh;   // [B,H,W,R]
    }

    __threadfence();        // make h/c/out visible at agent scope
    __syncthreads();        // all threads' stores issued+fenced before flag
    if (tid == 0)
      __hip_atomic_fetch_add(&flags[t], 1, __ATOMIC_RELEASE, __HIP_MEMORY_SCOPE_AGENT);
  }
}

// ---------------------------------------------------------------------------
extern "C" void kernel_launch(void* const* d_in, const int* in_sizes, int n_in,
                              void* d_out, int out_size, void* d_ws, size_t ws_size,
                              hipStream_t stream) {
  const float* x    = (const float*)d_in[0];   // [32,32,128,128]
  const float* W    = (const float*)d_in[1];   // [768,640]
  const float* bias = (const float*)d_in[2];   // [640]
  float* out = (float*)d_out;                  // [32,32,32,128]
  char* ws = (char*)d_ws;

  size_t off = 0;
  u16*   xs_h  = (u16*)(ws + off);  off += (size_t)32768 * 512 * 2;  // 33.6 MB
  u16*   xs_l  = (u16*)(ws + off);  off += (size_t)32768 * 512 * 2;  // 33.6 MB
  u16*   WxT_h = (u16*)(ws + off);  off += (size_t)640 * 512 * 2;
  u16*   WxT_l = (u16*)(ws + off);  off += (size_t)640 * 512 * 2;
  u16*   WhT_h = (u16*)(ws + off);  off += (size_t)640 * 256 * 2;
  u16*   WhT_l = (u16*)(ws + off);  off += (size_t)640 * 256 * 2;
  float* biasp = (float*)(ws + off); off += (size_t)640 * 4;
  float* Gp    = (float*)(ws + off); off += (size_t)32768 * 640 * 4; // 83.9 MB
  float* cbuf  = (float*)(ws + off); off += (size_t)32768 * 128 * 4; // 16.8 MB
  u16*   hbf_h = (u16*)(ws + off);  off += (size_t)32768 * 128 * 2;  // 8.4 MB
  u16*   hbf_l = (u16*)(ws + off);  off += (size_t)32768 * 128 * 2;  // 8.4 MB
  int*   flags = (int*)(ws + off);  off += 1024 * 4;
  (void)ws_size;

  hipMemsetAsync(flags, 0, 1024 * sizeof(int), stream);
  k_wprep<<<dim3(640), dim3(256), 0, stream>>>(W, bias, WxT_h, WxT_l, WhT_h, WhT_l, biasp);
  k_xgather<<<dim3(8192), dim3(256), 0, stream>>>(x, xs_h, xs_l);
  k_gemm_in<<<dim3(256, 5), dim3(256), 0, stream>>>(xs_h, xs_l, WxT_h, WxT_l, biasp, Gp);
  k_rec<<<dim3(512), dim3(128), 0, stream>>>(WhT_h, WhT_l, Gp, cbuf, hbf_h, hbf_l, out, flags);
}

// Round 5
// 879.818 us; speedup vs baseline: 2.6394x; 2.6394x over previous
//
#include <hip/hip_runtime.h>

// ---------------------------------------------------------------------------
// MultiDimensionalLSTM on MI355X.
// B=32, C=32, Y=X=128, win 4x4 -> grid 32x32 cells, F=512, R=128, gates 5R=640.
// Input projection hoisted to one split-bf16 MFMA GEMM. Recurrence: ONE
// persistent kernel, 512 WGs = (row h, r-slice si), wavefront sync:
//   data path: RELAXED agent-scope sc1 atomics (write/read-through at the
//     coherence point; consumers never acquire -> no buffer_inv ever).
//   publication: RELEASE fetch_add on flags[t] (vmcnt(0)+buffer_wbl2+atomic,
//     the architected cross-XCD release). All k_rec stores are sc1, so L2 has
//     no dirty lines and the wbl2 is cheap. R4's relaxed-flag publication was
//     NOT sufficient (absmax 2e-2 from stale reads); R3's acq_rel threadfence
//     (buffer_inv) cost 2.1 ms. This is the middle path.
// c_left in registers; split-bf16 (hi+lo, 3-term MFMA) everywhere; c fp32.
// ---------------------------------------------------------------------------

typedef unsigned short u16;
typedef unsigned int u32;
typedef unsigned long long u64;
typedef __attribute__((ext_vector_type(8))) short short8;     // 8 bf16 (4 VGPRs)
typedef __attribute__((ext_vector_type(8))) unsigned short us8;
typedef __attribute__((ext_vector_type(4))) float floatx4;

union Frag { u64 q[2]; short8 s; };

__device__ inline u16 f2bf(float f) {               // RNE fp32 -> bf16
  unsigned u = __float_as_uint(f);
  u += 0x7fffu + ((u >> 16) & 1u);
  return (u16)(u >> 16);
}
__device__ inline float bf2f(u16 v) { return __uint_as_float(((unsigned)v) << 16); }

__device__ inline void async16(u16* lds, const u16* g) {
  __builtin_amdgcn_global_load_lds((const __attribute__((address_space(1))) void*)g,
                                   (__attribute__((address_space(3))) void*)lds, 16, 0, 0);
}

__device__ inline float sigf(float x) { return 1.f / (1.f + __expf(-x)); }
__device__ inline float tanh_fast(float x) { return 1.f - 2.f / (__expf(2.f * x) + 1.f); }

// Relaxed agent-scope primitives: sc1 loads/stores, straight to coherence point.
__device__ inline void waitflag(const int* f, int target) {
  while (__hip_atomic_load(f, __ATOMIC_RELAXED, __HIP_MEMORY_SCOPE_AGENT) < target)
    __builtin_amdgcn_s_sleep(1);
  __asm__ __volatile__("" ::: "memory");   // compiler barrier: no load hoisting
}
__device__ inline u64 aload64(const u64* p) {
  return __hip_atomic_load(p, __ATOMIC_RELAXED, __HIP_MEMORY_SCOPE_AGENT);
}
__device__ inline void astore32(u32* p, u32 v) {
  __hip_atomic_store(p, v, __ATOMIC_RELAXED, __HIP_MEMORY_SCOPE_AGENT);
}
__device__ inline void astore64(u64* p, u64 v) {
  __hip_atomic_store(p, v, __ATOMIC_RELAXED, __HIP_MEMORY_SCOPE_AGENT);
}

// ---------------------------------------------------------------------------
// Prep 1: W [768][640] fp32 -> WxT_{h,l} [640 pcol][512 k], WhT_{h,l} [640][256],
// biasp [640]. pcol = r*5+g  <->  orig col g*128+r (gate-interleaved).
// ---------------------------------------------------------------------------
__global__ __launch_bounds__(256) void k_wprep(const float* __restrict__ W,
                                               const float* __restrict__ bias,
                                               u16* __restrict__ WxT_h, u16* __restrict__ WxT_l,
                                               u16* __restrict__ WhT_h, u16* __restrict__ WhT_l,
                                               float* __restrict__ biasp) {
  int pcol = blockIdx.x;                       // 0..639
  int col  = (pcol % 5) * 128 + pcol / 5;      // original gate column
  for (int k = threadIdx.x; k < 768; k += 256) {
    float v = W[(size_t)k * 640 + col];
    u16 hi = f2bf(v);
    u16 lo = f2bf(v - bf2f(hi));
    if (k < 512) { WxT_h[(size_t)pcol * 512 + k] = hi; WxT_l[(size_t)pcol * 512 + k] = lo; }
    else { WhT_h[(size_t)pcol * 256 + (k - 512)] = hi; WhT_l[(size_t)pcol * 256 + (k - 512)] = lo; }
  }
  if (threadIdx.x == 0) biasp[pcol] = bias[col];
}

// ---------------------------------------------------------------------------
// Prep 2: gather x [B,C,Y,X] -> xs hi/lo [t][b][f].
// xs[t][b][f] = x[b][f&31][t>>3][(t&7)*16 + (f>>5)]
// ---------------------------------------------------------------------------
__global__ __launch_bounds__(256) void k_xgather(const float* __restrict__ x,
                                                 u16* __restrict__ xs_h,
                                                 u16* __restrict__ xs_l) {
  int lane = threadIdx.x & 63;
  int pair = blockIdx.x * 4 + (threadIdx.x >> 6);  // t*32+b
  int t = pair >> 5, b = pair & 31;
  int y = t >> 3, x0 = (t & 7) * 16;
  int j = lane >> 2;
  int cbase = (lane & 3) * 8;
  const float* src = x + ((size_t)b * 32 * 128 + y) * 128 + x0 + j;
  us8 vh, vl;
#pragma unroll
  for (int u = 0; u < 8; ++u) {
    float f = src[(size_t)(cbase + u) * 16384];
    u16 hi = f2bf(f);
    vh[u] = hi;
    vl[u] = f2bf(f - bf2f(hi));
  }
  *(us8*)(xs_h + (size_t)pair * 512 + lane * 8) = vh;
  *(us8*)(xs_l + (size_t)pair * 512 + lane * 8) = vl;
}

// ---------------------------------------------------------------------------
// Input GEMM (split-bf16): M=32768, N=640, K=512. 128x128 tile, BK=32.
// ---------------------------------------------------------------------------
__global__ __launch_bounds__(256) void k_gemm_in(const u16* __restrict__ xs_h,
                                                 const u16* __restrict__ xs_l,
                                                 const u16* __restrict__ WxT_h,
                                                 const u16* __restrict__ WxT_l,
                                                 const float* __restrict__ biasp,
                                                 float* __restrict__ Gp) {
  __shared__ u16 Ah[128 * 32], Al[128 * 32];
  __shared__ u16 Bh[128 * 32], Bl[128 * 32];
  const int tid = threadIdx.x;
  const int wv = tid >> 6, lane = tid & 63;
  const int quad = lane >> 4, l16 = lane & 15;
  const int m0 = blockIdx.x * 128;
  const int n0 = blockIdx.y * 128;
  const int arow = lane >> 2;
  const int acol = (lane & 3) * 8;

  floatx4 acc[4][4] = {};

  for (int kt = 0; kt < 512; kt += 32) {
#pragma unroll
    for (int i = 0; i < 2; ++i) {
      int chunk = wv * 2 + i;
      int row = chunk * 16 + arow;
      size_t aoff = (size_t)(m0 + row) * 512 + kt + acol;
      size_t boff = (size_t)(n0 + row) * 512 + kt + acol;
      async16(&Ah[chunk * 512 + lane * 8], xs_h + aoff);
      async16(&Al[chunk * 512 + lane * 8], xs_l + aoff);
      async16(&Bh[chunk * 512 + lane * 8], WxT_h + boff);
      async16(&Bl[chunk * 512 + lane * 8], WxT_l + boff);
    }
    __syncthreads();
    short8 afh[4], afl[4], bfh[4], bfl[4];
#pragma unroll
    for (int mt = 0; mt < 4; ++mt) {
      int ro = ((wv & 1) * 64 + mt * 16 + l16) * 32 + quad * 8;
      afh[mt] = *(const short8*)&Ah[ro];
      afl[mt] = *(const short8*)&Al[ro];
    }
#pragma unroll
    for (int nt = 0; nt < 4; ++nt) {
      int ro = ((wv >> 1) * 64 + nt * 16 + l16) * 32 + quad * 8;
      bfh[nt] = *(const short8*)&Bh[ro];
      bfl[nt] = *(const short8*)&Bl[ro];
    }
#pragma unroll
    for (int mt = 0; mt < 4; ++mt)
#pragma unroll
      for (int nt = 0; nt < 4; ++nt) {
        floatx4 a = acc[mt][nt];
        a = __builtin_amdgcn_mfma_f32_16x16x32_bf16(afl[mt], bfh[nt], a, 0, 0, 0);
        a = __builtin_amdgcn_mfma_f32_16x16x32_bf16(afh[mt], bfl[nt], a, 0, 0, 0);
        a = __builtin_amdgcn_mfma_f32_16x16x32_bf16(afh[mt], bfh[nt], a, 0, 0, 0);
        acc[mt][nt] = a;
      }
    __syncthreads();
  }
#pragma unroll
  for (int nt = 0; nt < 4; ++nt) {
    int n = n0 + (wv >> 1) * 64 + nt * 16 + l16;
    float bv = biasp[n];
#pragma unroll
    for (int mt = 0; mt < 4; ++mt) {
      int m = m0 + (wv & 1) * 64 + mt * 16 + quad * 4;
#pragma unroll
      for (int r = 0; r < 4; ++r)
        Gp[(size_t)(m + r) * 640 + n] = acc[mt][nt][r] + bv;
    }
  }
}

// ---------------------------------------------------------------------------
// Persistent recurrence. Grid 512: blockIdx = si + 16*h (producers of row h-1
// have lower IDs -> forward progress under partial residency; LDS 54 KB ->
// 2 WGs/CU -> all 512 resident). Block 128 (2 waves).
// Slice si owns pcols [si*40,si*40+40) == r in [si*8,si*8+8).
// ---------------------------------------------------------------------------
__global__ __launch_bounds__(128) void k_rec(const u16* __restrict__ WhT_h,
                                             const u16* __restrict__ WhT_l,
                                             const float* __restrict__ Gp,
                                             u64* __restrict__ cbuf,       // [t*32+b][64] fp32 pairs
                                             u16* __restrict__ hbf_h,      // [t*32+b][128]
                                             u16* __restrict__ hbf_l,
                                             float* __restrict__ out,
                                             int* __restrict__ flags) {
  __shared__ u16 Bh[48 * 256], Bl[48 * 256];   // 24 KB each
  __shared__ float Gs[32 * 40];                // 5 KB
  const int si = blockIdx.x & 15, h = blockIdx.x >> 4;
  const int tid = threadIdx.x;
  const int wv = tid >> 6, lane = tid & 63;
  const int quad = lane >> 4, l16 = lane & 15;
  const int eb = tid >> 2;          // epilogue batch 0..31
  const int erp = tid & 3;          // epilogue r-pair 0..3 (r = si*8+erp*2+{0,1})

  { // stage B slice rows [si*40, si*40+40): 1 KB per async16 wave-call
    const u16* sh = WhT_h + (size_t)si * 40 * 256;
    const u16* sl = WhT_l + (size_t)si * 40 * 256;
#pragma unroll
    for (int c = 0; c < 10; ++c) {
      int rb = c * 4 + wv * 2;
      async16(&Bh[rb * 256 + lane * 8], sh + (size_t)rb * 256 + lane * 8);
      async16(&Bl[rb * 256 + lane * 8], sl + (size_t)rb * 256 + lane * 8);
    }
  }
  __syncthreads();

  float cleft0 = 0.f, cleft1 = 0.f;

  for (int w = 0; w < 32; ++w) {
    const int t = h * 32 + w;
    const bool upok = t > 32;            // faithful off-by-one: (1,0) gets no up
    const bool leftok = w > 0;

    // Gp prefetch (plain cached loads; no dependency on flags)
    float gpre[3][4];
#pragma unroll
    for (int nt = 0; nt < 3; ++nt) {
      int pl = nt * 16 + l16;
#pragma unroll
      for (int r = 0; r < 4; ++r) {
        int b = wv * 16 + quad * 4 + r;
        gpre[nt][r] = (pl < 40) ? Gp[((size_t)t * 32 + b) * 640 + si * 40 + pl] : 0.f;
      }
    }

    floatx4 acc[3] = {};
    float c1p0 = 0.f, c1p1 = 0.f;

    if (upok) {                          // up half: wait, load, MFMA
      waitflag(&flags[t - 32], 16);
      Frag fh[4], fl[4];
#pragma unroll
      for (int ks = 0; ks < 4; ++ks) {
        size_t bi = (((size_t)(t - 32) * 32 + wv * 16 + l16) * 128 + ks * 32 + quad * 8) >> 2;
        fh[ks].q[0] = aload64((const u64*)hbf_h + bi);
        fh[ks].q[1] = aload64((const u64*)hbf_h + bi + 1);
        fl[ks].q[0] = aload64((const u64*)hbf_l + bi);
        fl[ks].q[1] = aload64((const u64*)hbf_l + bi + 1);
      }
      u64 cp = aload64(cbuf + ((size_t)(t - 32) * 32 + eb) * 64 + si * 4 + erp);
      c1p0 = __uint_as_float((u32)cp);
      c1p1 = __uint_as_float((u32)(cp >> 32));
#pragma unroll
      for (int ks = 0; ks < 4; ++ks)
#pragma unroll
        for (int nt = 0; nt < 3; ++nt) {
          int bo = (nt * 16 + l16) * 256 + ks * 32 + quad * 8;
          short8 bh = *(const short8*)&Bh[bo];
          short8 bl = *(const short8*)&Bl[bo];
          floatx4 a = acc[nt];
          a = __builtin_amdgcn_mfma_f32_16x16x32_bf16(fl[ks].s, bh, a, 0, 0, 0);
          a = __builtin_amdgcn_mfma_f32_16x16x32_bf16(fh[ks].s, bl, a, 0, 0, 0);
          a = __builtin_amdgcn_mfma_f32_16x16x32_bf16(fh[ks].s, bh, a, 0, 0, 0);
          acc[nt] = a;
        }
    }
    if (leftok) {                        // left half: wait, load, MFMA
      waitflag(&flags[t - 1], 16);
      Frag fh[4], fl[4];
#pragma unroll
      for (int ks = 0; ks < 4; ++ks) {
        size_t bi = (((size_t)(t - 1) * 32 + wv * 16 + l16) * 128 + ks * 32 + quad * 8) >> 2;
        fh[ks].q[0] = aload64((const u64*)hbf_h + bi);
        fh[ks].q[1] = aload64((const u64*)hbf_h + bi + 1);
        fl[ks].q[0] = aload64((const u64*)hbf_l + bi);
        fl[ks].q[1] = aload64((const u64*)hbf_l + bi + 1);
      }
#pragma unroll
      for (int ks = 0; ks < 4; ++ks)
#pragma unroll
        for (int nt = 0; nt < 3; ++nt) {
          int bo = (nt * 16 + l16) * 256 + (ks + 4) * 32 + quad * 8;
          short8 bh = *(const short8*)&Bh[bo];
          short8 bl = *(const short8*)&Bl[bo];
          floatx4 a = acc[nt];
          a = __builtin_amdgcn_mfma_f32_16x16x32_bf16(fl[ks].s, bh, a, 0, 0, 0);
          a = __builtin_amdgcn_mfma_f32_16x16x32_bf16(fh[ks].s, bl, a, 0, 0, 0);
          a = __builtin_amdgcn_mfma_f32_16x16x32_bf16(fh[ks].s, bh, a, 0, 0, 0);
          acc[nt] = a;
        }
    }

    // gates -> Gs  (D layout: row=quad*4+r -> b, col=l16 -> n-local)
#pragma unroll
    for (int nt = 0; nt < 3; ++nt) {
      int pl = nt * 16 + l16;
      if (pl < 40) {
#pragma unroll
        for (int r = 0; r < 4; ++r) {
          int b = wv * 16 + quad * 4 + r;
          Gs[b * 40 + pl] = acc[nt][r] + gpre[nt][r];
        }
      }
    }
    __syncthreads();

    // nonlinearity + state update: thread (eb, erp) handles r-pair
    const float* gp = &Gs[eb * 40 + erp * 10];
    float nc0, nc1, nh0, nh1;
    {
      float gi = gp[0], gj = gp[1], g1 = gp[2], g2 = gp[3], go = gp[4];
      float c2 = leftok ? cleft0 : 0.f;
      nc0 = c1p0 * sigf(g1) + c2 * sigf(g2) + sigf(gi) * tanh_fast(gj);
      nh0 = tanh_fast(nc0) * sigf(go);
    }
    {
      float gi = gp[5], gj = gp[6], g1 = gp[7], g2 = gp[8], go = gp[9];
      float c2 = leftok ? cleft1 : 0.f;
      nc1 = c1p1 * sigf(g1) + c2 * sigf(g2) + sigf(gi) * tanh_fast(gj);
      nh1 = tanh_fast(nc1) * sigf(go);
    }
    cleft0 = nc0; cleft1 = nc1;

    u32 hi0 = f2bf(nh0), lo0 = f2bf(nh0 - bf2f((u16)hi0));
    u32 hi1 = f2bf(nh1), lo1 = f2bf(nh1 - bf2f((u16)hi1));
    size_t pidx = ((size_t)t * 32 + eb) * 64 + si * 4 + erp;   // u32/u64 pair index
    astore32((u32*)hbf_h + pidx, hi0 | (hi1 << 16));
    astore32((u32*)hbf_l + pidx, lo0 | (lo1 << 16));
    u64 cpk = (u64)__float_as_uint(nc0) | ((u64)__float_as_uint(nc1) << 32);
    astore64(cbuf + pidx, cpk);
    int r0 = si * 8 + erp * 2;
    // out stored sc1 too: keeps L2 free of dirty lines so the release wbl2
    // below has nothing to write back.
    u64 opk = (u64)__float_as_uint(nh0) | ((u64)__float_as_uint(nh1) << 32);
    astore64((u64*)(out + (((size_t)eb * 32 + h) * 32 + w) * 128 + r0), opk);

    __syncthreads();   // all waves drain vmcnt before publication
    if (tid == 0)      // architected cross-XCD release: vmcnt(0)+wbl2+atomic
      __hip_atomic_fetch_add(&flags[t], 1, __ATOMIC_RELEASE, __HIP_MEMORY_SCOPE_AGENT);
  }
}

// ---------------------------------------------------------------------------
extern "C" void kernel_launch(void* const* d_in, const int* in_sizes, int n_in,
                              void* d_out, int out_size, void* d_ws, size_t ws_size,
                              hipStream_t stream) {
  const float* x    = (const float*)d_in[0];   // [32,32,128,128]
  const float* W    = (const float*)d_in[1];   // [768,640]
  const float* bias = (const float*)d_in[2];   // [640]
  float* out = (float*)d_out;                  // [32,32,32,128]
  char* ws = (char*)d_ws;

  size_t off = 0;
  u16*   xs_h  = (u16*)(ws + off);  off += (size_t)32768 * 512 * 2;  // 33.6 MB
  u16*   xs_l  = (u16*)(ws + off);  off += (size_t)32768 * 512 * 2;  // 33.6 MB
  u16*   WxT_h = (u16*)(ws + off);  off += (size_t)640 * 512 * 2;
  u16*   WxT_l = (u16*)(ws + off);  off += (size_t)640 * 512 * 2;
  u16*   WhT_h = (u16*)(ws + off);  off += (size_t)640 * 256 * 2;
  u16*   WhT_l = (u16*)(ws + off);  off += (size_t)640 * 256 * 2;
  float* biasp = (float*)(ws + off); off += (size_t)640 * 4;
  float* Gp    = (float*)(ws + off); off += (size_t)32768 * 640 * 4; // 83.9 MB
  u64*   cbuf  = (u64*)(ws + off);  off += (size_t)32768 * 64 * 8;   // 16.8 MB
  u16*   hbf_h = (u16*)(ws + off);  off += (size_t)32768 * 128 * 2;  // 8.4 MB
  u16*   hbf_l = (u16*)(ws + off);  off += (size_t)32768 * 128 * 2;  // 8.4 MB
  int*   flags = (int*)(ws + off);  off += 1024 * 4;
  (void)ws_size;

  hipMemsetAsync(flags, 0, 1024 * sizeof(int), stream);
  k_wprep<<<dim3(640), dim3(256), 0, stream>>>(W, bias, WxT_h, WxT_l, WhT_h, WhT_l, biasp);
  k_xgather<<<dim3(8192), dim3(256), 0, stream>>>(x, xs_h, xs_l);
  k_gemm_in<<<dim3(256, 5), dim3(256), 0, stream>>>(xs_h, xs_l, WxT_h, WxT_l, biasp, Gp);
  k_rec<<<dim3(512), dim3(128), 0, stream>>>(WhT_h, WhT_l, Gp, cbuf, hbf_h, hbf_l, out, flags);
}